// Round 10
// baseline (194.616 us; speedup 1.0000x reference)
//
#include <hip/hip_runtime.h>
#include <hip/hip_bf16.h>
#include <cstdint>

#define B_ROWS 16384
#define NCLS 1000
#define NPAD 1024
#define FDIM 768
#define TEMP_INV 10.0f
#define BCAP 128

typedef float floatx4 __attribute__((ext_vector_type(4)));
typedef short short8 __attribute__((ext_vector_type(8)));
typedef unsigned short ushort8v __attribute__((ext_vector_type(8)));

__device__ inline unsigned short f2bf(float f) {
  unsigned int u = __float_as_uint(f);
  u += 0x7FFFu + ((u >> 16) & 1u);   // round-to-nearest-even
  return (unsigned short)(u >> 16);
}

__device__ inline unsigned int pkbf(float a, float b) {
  // pack 2 fp32 -> 2 bf16 (RTNE), low = a, high = b
  return (unsigned int)f2bf(a) | ((unsigned int)f2bf(b) << 16);
}

#define GLDS(gp, lp) __builtin_amdgcn_global_load_lds( \
    (const __attribute__((address_space(1))) void*)(gp), \
    (__attribute__((address_space(3))) void*)(lp), 16, 0, 0)

#define CVTC_BLOCKS 384     // 1024*768/8/256 (centers only)
#define GEMM_BLOCKS 2048    // 256 rowblks x 8 colblks (64x128 tiles)
#define CE_BLOCKS  4096     // 16384/4

// ---------------- cvt: centers fp32 -> bf16, zero-padded to 1024 rows (~3 us)
__global__ __launch_bounds__(256) void cvt_kernel(
    const float* __restrict__ centers, unsigned short* __restrict__ cbf) {
  int j = blockIdx.x * 256 + threadIdx.x;
  float4 v0, v1;
  if (j * 8 < NCLS * FDIM) {
    const float4* s = reinterpret_cast<const float4*>(centers) + (size_t)j * 2;
    v0 = s[0]; v1 = s[1];
  } else {
    v0.x = v0.y = v0.z = v0.w = 0.f;
    v1 = v0;
  }
  ushort8v o;
  o[0] = f2bf(v0.x); o[1] = f2bf(v0.y); o[2] = f2bf(v0.z); o[3] = f2bf(v0.w);
  o[4] = f2bf(v1.x); o[5] = f2bf(v1.y); o[6] = f2bf(v1.z); o[7] = f2bf(v1.w);
  *reinterpret_cast<ushort8v*>(cbf + (size_t)j * 8) = o;
}

// ---------------- GEMM 64x128 BK=64 (+tail CE blocks) + softmax partials.
// R6-measured gemm structure (57.5 us fused, 0 conflicts), with A staged
// IN-KERNEL from fp32 features (load -> bf16 pack -> swizzled ds_write_b128),
// eliminating the fbf round-trip and most of the cvt dispatch.
__global__ __launch_bounds__(256) void gemm_stats_kernel(
    const float* __restrict__ features,
    const unsigned short* __restrict__ cbf,
    const int* __restrict__ labels,
    const float* __restrict__ outputs,
    float* __restrict__ ce_partial,
    float* __restrict__ pm, float* __restrict__ psv,
    float* __restrict__ ztrue, int* __restrict__ bcnt) {
  __shared__ __align__(16) unsigned short As[64 * 64];    // 8 KB
  __shared__ __align__(16) unsigned short Bs[128 * 64];   // 16 KB
  __shared__ int lab[64];
  __shared__ float sm[64][2], ss[64][2];
  __shared__ float ared[4];

  const int t = threadIdx.x;
  const int bid = blockIdx.x;

  if (bid >= GEMM_BLOCKS) {
    // ---- CE path: one wave per row, 4 rows/block (R6-measured)
    const int cb = bid - GEMM_BLOCKS;        // 0..4095
    const int wid = t >> 6;
    const int lane = t & 63;
    const int b = cb * 4 + wid;
    const float* row = outputs + (size_t)b * NCLS;
    const float4* r4 = reinterpret_cast<const float4*>(row);
    float4 v[4];
    float m = -1e30f;
#pragma unroll
    for (int it = 0; it < 4; ++it) {
      int idx = lane + it * 64;
      if (idx < 250) v[it] = r4[idx];
      else { v[it].x = -1e30f; v[it].y = -1e30f; v[it].z = -1e30f; v[it].w = -1e30f; }
      m = fmaxf(m, fmaxf(fmaxf(v[it].x, v[it].y), fmaxf(v[it].z, v[it].w)));
    }
#pragma unroll
    for (int msk = 1; msk < 64; msk <<= 1) m = fmaxf(m, __shfl_xor(m, msk));
    float s = 0.f;
#pragma unroll
    for (int it = 0; it < 4; ++it)
      s += __expf(v[it].x - m) + __expf(v[it].y - m) + __expf(v[it].z - m) + __expf(v[it].w - m);
#pragma unroll
    for (int msk = 1; msk < 64; msk <<= 1) s += __shfl_xor(s, msk);
    if (lane == 0) {
      float lse = m + logf(s);
      ared[wid] = lse - row[labels[b]];
    }
    __syncthreads();
    if (t == 0)
      ce_partial[cb] = ared[0] + ared[1] + ared[2] + ared[3];
    return;
  }

  // ---- GEMM path
  if (t == 0 && bid < NCLS) bcnt[bid] = 0;   // zero bucket counters for combine

  const int rowblk = (bid & 7) + 8 * (bid >> 6);   // 0..255; 8 colblks share an XCD
  const int colblk = (bid >> 3) & 7;               // 0..7
  const int w = t >> 6, lane = t & 63;
  const int quad = lane >> 4, l15 = lane & 15;
  const int wr = w >> 1, wc = w & 1;

  if (t < 64) lab[t] = labels[rowblk * 64 + t];

  // B staging (GLDS, R6-proven): chunk c -> LDS c*16; global piece = (c&7)^(row&7)
  const int tq = t >> 3, tr = t & 7;               // tq 0..31, tr 0..7
  const int gp = tr ^ (tq & 7);
  const unsigned short* bgp0 = cbf + (size_t)(colblk * 128 + 0 * 32 + tq) * FDIM + gp * 8;
  const unsigned short* bgp1 = cbf + (size_t)(colblk * 128 + 1 * 32 + tq) * FDIM + gp * 8;
  const unsigned short* bgp2 = cbf + (size_t)(colblk * 128 + 2 * 32 + tq) * FDIM + gp * 8;
  const unsigned short* bgp3 = cbf + (size_t)(colblk * 128 + 3 * 32 + tq) * FDIM + gp * 8;
  unsigned short* bl0 = &Bs[(0 * 256 + w * 64) * 8];
  unsigned short* bl1 = &Bs[(1 * 256 + w * 64) * 8];
  unsigned short* bl2 = &Bs[(2 * 256 + w * 64) * 8];
  unsigned short* bl3 = &Bs[(3 * 256 + w * 64) * 8];

  // A staging from fp32 features: thread t handles chunks t and 256+t
  // (row = tq / 32+tq, piece = tr); LDS swizzle (tr^(tq&7)) applied on write.
  const float* agf0 = features + (size_t)(rowblk * 64 + tq) * FDIM + tr * 8;
  const float* agf1 = agf0 + (size_t)32 * FDIM;
  unsigned short* aw0 = &As[(tq * 8 + gp) * 8];          // (32+tq)&7 == tq&7
  unsigned short* aw1 = aw0 + 32 * 64;

  const int swz = l15 & 7;

  floatx4 acc[2][4];
#pragma unroll
  for (int i = 0; i < 2; ++i)
#pragma unroll
    for (int j = 0; j < 4; ++j) acc[i][j] = (floatx4){0.f, 0.f, 0.f, 0.f};

#pragma unroll
  for (int kk = 0; kk < 12; ++kk) {
    __syncthreads();                       // prev tile fully consumed
    const int ko = kk * 64;
    GLDS(bgp0 + ko, bl0);
    GLDS(bgp1 + ko, bl1);
    GLDS(bgp2 + ko, bl2);
    GLDS(bgp3 + ko, bl3);
    {
      float4 u0 = *reinterpret_cast<const float4*>(agf0 + ko);
      float4 u1 = *reinterpret_cast<const float4*>(agf0 + ko + 4);
      float4 u2 = *reinterpret_cast<const float4*>(agf1 + ko);
      float4 u3 = *reinterpret_cast<const float4*>(agf1 + ko + 4);
      uint4 w0, w1;
      w0.x = pkbf(u0.x, u0.y); w0.y = pkbf(u0.z, u0.w);
      w0.z = pkbf(u1.x, u1.y); w0.w = pkbf(u1.z, u1.w);
      w1.x = pkbf(u2.x, u2.y); w1.y = pkbf(u2.z, u2.w);
      w1.z = pkbf(u3.x, u3.y); w1.w = pkbf(u3.z, u3.w);
      *reinterpret_cast<uint4*>(aw0) = w0;
      *reinterpret_cast<uint4*>(aw1) = w1;
    }
    __syncthreads();                       // tile resident
    short8 a[2][2], b[4][2];
#pragma unroll
    for (int ks = 0; ks < 2; ++ks) {
      const int qs = ((ks * 4 + quad) ^ swz) * 8;
#pragma unroll
      for (int rb = 0; rb < 2; ++rb)
        a[rb][ks] = *reinterpret_cast<const short8*>(&As[(wr * 32 + rb * 16 + l15) * 64 + qs]);
#pragma unroll
      for (int cb = 0; cb < 4; ++cb)
        b[cb][ks] = *reinterpret_cast<const short8*>(&Bs[(wc * 64 + cb * 16 + l15) * 64 + qs]);
    }
#pragma unroll
    for (int ks = 0; ks < 2; ++ks)
#pragma unroll
      for (int rb = 0; rb < 2; ++rb)
#pragma unroll
        for (int cb = 0; cb < 4; ++cb)
          acc[rb][cb] = __builtin_amdgcn_mfma_f32_16x16x32_bf16(a[rb][ks], b[cb][ks], acc[rb][cb], 0, 0, 0);
  }

  // epilogue: z = 10*sims; per-row partial max/sumexp over this block's 128 cols
  const int gcol0 = colblk * 128 + wc * 64;
#pragma unroll
  for (int rb = 0; rb < 2; ++rb) {
#pragma unroll
    for (int r = 0; r < 4; ++r) {
      const int lrow = wr * 32 + rb * 16 + quad * 4 + r;
      float zv[4];
      float m = -1e30f;
#pragma unroll
      for (int cb = 0; cb < 4; ++cb) {
        float z = acc[rb][cb][r] * TEMP_INV;
        int gc = gcol0 + cb * 16 + l15;
        if (gc == lab[lrow]) ztrue[rowblk * 64 + lrow] = z;
        if (gc >= NCLS) z = -1e30f;
        zv[cb] = z;
        m = fmaxf(m, z);
      }
#pragma unroll
      for (int msk = 1; msk < 16; msk <<= 1) m = fmaxf(m, __shfl_xor(m, msk));
      float s = 0.f;
#pragma unroll
      for (int cb = 0; cb < 4; ++cb) s += __expf(zv[cb] - m);
#pragma unroll
      for (int msk = 1; msk < 16; msk <<= 1) s += __shfl_xor(s, msk);
      if (l15 == 0) { sm[lrow][wc] = m; ss[lrow][wc] = s; }
    }
  }
  __syncthreads();
  if (t < 64) {
    float m0 = sm[t][0], m1 = sm[t][1];
    float mn = fmaxf(m0, m1);
    float S = ss[t][0] * __expf(m0 - mn) + ss[t][1] * __expf(m1 - mn);
    int grow = rowblk * 64 + t;
    pm[colblk * B_ROWS + grow] = mn;
    psv[colblk * B_ROWS + grow] = S;
  }
}

// ---------------- combine: merge partials -> p, SDC partials, class buckets
__global__ __launch_bounds__(256) void combine_kernel(
    const float* __restrict__ pm, const float* __restrict__ psv,
    const float* __restrict__ ztrue, const int* __restrict__ labels,
    int* __restrict__ bcnt, int* __restrict__ bidx, float* __restrict__ bp,
    float* __restrict__ sdc_partial) {
  __shared__ float wred[4];
  const int b = blockIdx.x * 256 + threadIdx.x;
  float mj[8];
  float M = -1e30f;
#pragma unroll
  for (int j = 0; j < 8; ++j) { mj[j] = pm[j * B_ROWS + b]; M = fmaxf(M, mj[j]); }
  float S = 0.f;
#pragma unroll
  for (int j = 0; j < 8; ++j) S += psv[j * B_ROWS + b] * __expf(mj[j] - M);
  float p = __expf(ztrue[b] - M) / S;
  int lb = labels[b];
  int slot = atomicAdd(&bcnt[lb], 1);
  if (slot < BCAP) { bidx[lb * BCAP + slot] = b; bp[lb * BCAP + slot] = p; }
  float v = -logf(p + 1e-8f);
#pragma unroll
  for (int msk = 1; msk < 64; msk <<= 1) v += __shfl_xor(v, msk);
  if ((threadIdx.x & 63) == 0) wred[threadIdx.x >> 6] = v;
  __syncthreads();
  if (threadIdx.x == 0)
    sdc_partial[blockIdx.x] = wred[0] + wred[1] + wred[2] + wred[3];
}

// ---------------- mstep: one block per class, direct bucket gather.
// Block 0 additionally finalizes the scalar loss.
__global__ __launch_bounds__(256) void mstep_kernel(
    const float* __restrict__ features,
    const float* __restrict__ centers,
    const int* __restrict__ bcnt, const int* __restrict__ bidx,
    const float* __restrict__ bp,
    const float* __restrict__ ce_partial, const float* __restrict__ sdc_partial,
    float* __restrict__ out_loss, float* __restrict__ out_centers) {
  const int c = blockIdx.x;
  const int t = threadIdx.x;
  if (c == 0) {
    __shared__ float red[256];
    float s = 0.f;
    for (int i = t; i < CE_BLOCKS; i += 256) s += ce_partial[i];
    float s2 = 0.f;
    for (int i = t; i < 64; i += 256) s2 += sdc_partial[i];
    red[t] = s + 0.1f * s2;
    __syncthreads();
    for (int off = 128; off > 0; off >>= 1) {
      if (t < off) red[t] += red[t + off];
      __syncthreads();
    }
    if (t == 0) out_loss[0] = red[0] * (1.0f / 16384.0f);
  }
  int n = bcnt[c];
  if (n > BCAP) n = BCAP;
  float a0 = 0.f, a1 = 0.f, a2 = 0.f, ws = 0.f;
  int j = 0;
  for (; j + 2 <= n; j += 2) {
    int b0 = bidx[c * BCAP + j], b1 = bidx[c * BCAP + j + 1];
    float p0 = bp[c * BCAP + j], p1 = bp[c * BCAP + j + 1];
    const float* f0 = features + (size_t)b0 * FDIM;
    const float* f1 = features + (size_t)b1 * FDIM;
    float x00 = f0[t], x01 = f0[t + 256], x02 = f0[t + 512];
    float x10 = f1[t], x11 = f1[t + 256], x12 = f1[t + 512];
    a0 += p0 * x00 + p1 * x10;
    a1 += p0 * x01 + p1 * x11;
    a2 += p0 * x02 + p1 * x12;
    ws += p0 + p1;
  }
  if (j < n) {
    int b0 = bidx[c * BCAP + j];
    float p0 = bp[c * BCAP + j];
    const float* f0 = features + (size_t)b0 * FDIM;
    a0 += p0 * f0[t]; a1 += p0 * f0[t + 256]; a2 += p0 * f0[t + 512];
    ws += p0;
  }
  const float* crow = centers + (size_t)c * FDIM;
  float c0 = crow[t], c1 = crow[t + 256], c2 = crow[t + 512];
  size_t o = (size_t)c * FDIM + t;
  if (ws > 0.f) {
    float inv = 0.1f / (ws + 1e-8f);
    out_centers[o]       = 0.9f * c0 + a0 * inv;
    out_centers[o + 256] = 0.9f * c1 + a1 * inv;
    out_centers[o + 512] = 0.9f * c2 + a2 * inv;
  } else {
    out_centers[o]       = c0;
    out_centers[o + 256] = c1;
    out_centers[o + 512] = c2;
  }
}

extern "C" void kernel_launch(void* const* d_in, const int* in_sizes, int n_in,
                              void* d_out, int out_size, void* d_ws, size_t ws_size,
                              hipStream_t stream) {
  const float* outputs  = (const float*)d_in[0];
  const int*   labels   = (const int*)d_in[1];
  const float* features = (const float*)d_in[2];
  const float* centers  = (const float*)d_in[3];
  float* out = (float*)d_out;

  char* ws = (char*)d_ws;
  float* ztrue       = (float*)(ws);                          // 64 KB
  float* ce_partial  = (float*)(ws + (64 << 10));             // 16 KB
  float* sdc_partial = (float*)(ws + (80 << 10));             // 256 B
  int*   bcnt        = (int*)(ws + (84 << 10));               // 4 KB
  float* pm          = (float*)(ws + (88 << 10));             // 512 KB
  float* psv         = (float*)(ws + (600 << 10));            // 512 KB
  unsigned short* cbf = (unsigned short*)(ws + (1112 << 10)); // 1.5 MB
  int*   bidx        = (int*)(ws + (2648 << 10));             // 512 KB
  float* bp          = (float*)(ws + (3160 << 10));           // 512 KB

  cvt_kernel<<<CVTC_BLOCKS, 256, 0, stream>>>(centers, cbf);
  gemm_stats_kernel<<<GEMM_BLOCKS + CE_BLOCKS, 256, 0, stream>>>(
      features, cbf, labels, outputs, ce_partial, pm, psv, ztrue, bcnt);
  combine_kernel<<<B_ROWS / 256, 256, 0, stream>>>(pm, psv, ztrue, labels,
                                                   bcnt, bidx, bp, sdc_partial);
  mstep_kernel<<<NCLS, 256, 0, stream>>>(features, centers, bcnt, bidx, bp,
                                         ce_partial, sdc_partial, out, out + 1);
}

// Round 11
// 187.267 us; speedup vs baseline: 1.0392x; 1.0392x over previous
//
#include <hip/hip_runtime.h>
#include <hip/hip_bf16.h>
#include <cstdint>

#define B_ROWS 16384
#define NCLS 1000
#define NPAD 1024
#define FDIM 768
#define TEMP_INV 10.0f
#define BCAP 128

typedef float floatx4 __attribute__((ext_vector_type(4)));
typedef short short8 __attribute__((ext_vector_type(8)));
typedef unsigned short ushort8v __attribute__((ext_vector_type(8)));

__device__ inline unsigned short f2bf(float f) {
  unsigned int u = __float_as_uint(f);
  u += 0x7FFFu + ((u >> 16) & 1u);   // round-to-nearest-even
  return (unsigned short)(u >> 16);
}

#define GLDS(gp, lp) __builtin_amdgcn_global_load_lds( \
    (const __attribute__((address_space(1))) void*)(gp), \
    (__attribute__((address_space(3))) void*)(lp), 16, 0, 0)

#define CVT_BLOCKS 6528     // (16384*768 + 1024*768)/8/256
#define GEMM_BLOCKS 2048
#define CE_BLOCKS  4096     // 16384/4

// ---------------- cvt: features+centers fp32 -> bf16 (centers zero-padded)
__global__ __launch_bounds__(256) void cvt_kernel(
    const float* __restrict__ features, const float* __restrict__ centers,
    unsigned short* __restrict__ fbf, unsigned short* __restrict__ cbf) {
  const int NF8 = B_ROWS * FDIM / 8;
  int i = blockIdx.x * 256 + threadIdx.x;
  float4 v0, v1;
  unsigned short* dst;
  if (i < NF8) {
    const float4* s = reinterpret_cast<const float4*>(features) + (size_t)i * 2;
    v0 = s[0]; v1 = s[1];
    dst = fbf + (size_t)i * 8;
  } else {
    int j = i - NF8;
    if (j * 8 < NCLS * FDIM) {
      const float4* s = reinterpret_cast<const float4*>(centers) + (size_t)j * 2;
      v0 = s[0]; v1 = s[1];
    } else {
      v0.x = v0.y = v0.z = v0.w = 0.f;
      v1 = v0;
    }
    dst = cbf + (size_t)j * 8;
  }
  ushort8v o;
  o[0] = f2bf(v0.x); o[1] = f2bf(v0.y); o[2] = f2bf(v0.z); o[3] = f2bf(v0.w);
  o[4] = f2bf(v1.x); o[5] = f2bf(v1.y); o[6] = f2bf(v1.z); o[7] = f2bf(v1.w);
  *reinterpret_cast<ushort8v*>(dst) = o;
}

// ---------------- GEMM (+tail CE blocks) + per-colblock softmax partials.
// Blocks 0..2047: 64x128 tile, BK=64, single-buffer GLDS, XOR-swizzled LDS
// (0 bank conflicts). Blocks 2048..6143: CE rows. R6-measured optimum:
// 57.5 us fused; all structural alternatives (dbuf+vmcnt, interleave, 128x128,
// in-kernel A-cvt) measured worse in R5/R7/R9/R10.
__global__ __launch_bounds__(256) void gemm_stats_kernel(
    const unsigned short* __restrict__ fbf,
    const unsigned short* __restrict__ cbf,
    const int* __restrict__ labels,
    const float* __restrict__ outputs,
    float* __restrict__ ce_partial,
    float* __restrict__ pm, float* __restrict__ psv,
    float* __restrict__ ztrue, int* __restrict__ bcnt) {
  __shared__ __align__(16) unsigned short As[64 * 64];    // 8 KB
  __shared__ __align__(16) unsigned short Bs[128 * 64];   // 16 KB
  __shared__ int lab[64];
  __shared__ float sm[64][2], ss[64][2];
  __shared__ float ared[4];

  const int t = threadIdx.x;
  const int bid = blockIdx.x;

  if (bid >= GEMM_BLOCKS) {
    // ---- CE path: one wave per row, 4 rows/block
    const int cb = bid - GEMM_BLOCKS;
    const int wid = t >> 6;
    const int lane = t & 63;
    const int b = cb * 4 + wid;
    const float* row = outputs + (size_t)b * NCLS;
    const float4* r4 = reinterpret_cast<const float4*>(row);
    float4 v[4];
    float m = -1e30f;
#pragma unroll
    for (int it = 0; it < 4; ++it) {
      int idx = lane + it * 64;
      if (idx < 250) v[it] = r4[idx];
      else { v[it].x = -1e30f; v[it].y = -1e30f; v[it].z = -1e30f; v[it].w = -1e30f; }
      m = fmaxf(m, fmaxf(fmaxf(v[it].x, v[it].y), fmaxf(v[it].z, v[it].w)));
    }
#pragma unroll
    for (int msk = 1; msk < 64; msk <<= 1) m = fmaxf(m, __shfl_xor(m, msk));
    float s = 0.f;
#pragma unroll
    for (int it = 0; it < 4; ++it)
      s += __expf(v[it].x - m) + __expf(v[it].y - m) + __expf(v[it].z - m) + __expf(v[it].w - m);
#pragma unroll
    for (int msk = 1; msk < 64; msk <<= 1) s += __shfl_xor(s, msk);
    if (lane == 0) {
      float lse = m + logf(s);
      ared[wid] = lse - row[labels[b]];
    }
    __syncthreads();
    if (t == 0)
      ce_partial[cb] = ared[0] + ared[1] + ared[2] + ared[3];
    return;
  }

  // ---- GEMM path
  if (t == 0 && bid < NCLS) bcnt[bid] = 0;   // zero bucket counters for combine

  const int rowblk = (bid & 7) + 8 * (bid >> 6);   // 0..255; 8 colblks share an XCD
  const int colblk = (bid >> 3) & 7;               // 0..7
  const int w = t >> 6, lane = t & 63;
  const int quad = lane >> 4, l15 = lane & 15;
  const int wr = w >> 1, wc = w & 1;

  if (t < 64) lab[t] = labels[rowblk * 64 + t];

  // staging: chunk p (16B) -> LDS offset p*16; global piece = (p&7)^(row&7)
  const int tq = t >> 3, tr = t & 7;
  const int gp = tr ^ (tq & 7);
  const unsigned short* agp0 = fbf + (size_t)(rowblk * 64 + 0 * 32 + tq) * FDIM + gp * 8;
  const unsigned short* agp1 = fbf + (size_t)(rowblk * 64 + 1 * 32 + tq) * FDIM + gp * 8;
  const unsigned short* bgp0 = cbf + (size_t)(colblk * 128 + 0 * 32 + tq) * FDIM + gp * 8;
  const unsigned short* bgp1 = cbf + (size_t)(colblk * 128 + 1 * 32 + tq) * FDIM + gp * 8;
  const unsigned short* bgp2 = cbf + (size_t)(colblk * 128 + 2 * 32 + tq) * FDIM + gp * 8;
  const unsigned short* bgp3 = cbf + (size_t)(colblk * 128 + 3 * 32 + tq) * FDIM + gp * 8;
  unsigned short* al0 = &As[(0 * 256 + w * 64) * 8];
  unsigned short* al1 = &As[(1 * 256 + w * 64) * 8];
  unsigned short* bl0 = &Bs[(0 * 256 + w * 64) * 8];
  unsigned short* bl1 = &Bs[(1 * 256 + w * 64) * 8];
  unsigned short* bl2 = &Bs[(2 * 256 + w * 64) * 8];
  unsigned short* bl3 = &Bs[(3 * 256 + w * 64) * 8];

  const int swz = l15 & 7;

  floatx4 acc[2][4];
#pragma unroll
  for (int i = 0; i < 2; ++i)
#pragma unroll
    for (int j = 0; j < 4; ++j) acc[i][j] = (floatx4){0.f, 0.f, 0.f, 0.f};

#pragma unroll
  for (int kk = 0; kk < 12; ++kk) {
    __syncthreads();                       // prev tile fully consumed
    const int ko = kk * 64;
    GLDS(agp0 + ko, al0);
    GLDS(agp1 + ko, al1);
    GLDS(bgp0 + ko, bl0);
    GLDS(bgp1 + ko, bl1);
    GLDS(bgp2 + ko, bl2);
    GLDS(bgp3 + ko, bl3);
    __syncthreads();                       // tile resident
    short8 a[2][2], b[4][2];
#pragma unroll
    for (int ks = 0; ks < 2; ++ks) {
      const int qs = ((ks * 4 + quad) ^ swz) * 8;
#pragma unroll
      for (int rb = 0; rb < 2; ++rb)
        a[rb][ks] = *reinterpret_cast<const short8*>(&As[(wr * 32 + rb * 16 + l15) * 64 + qs]);
#pragma unroll
      for (int cb = 0; cb < 4; ++cb)
        b[cb][ks] = *reinterpret_cast<const short8*>(&Bs[(wc * 64 + cb * 16 + l15) * 64 + qs]);
    }
#pragma unroll
    for (int ks = 0; ks < 2; ++ks)
#pragma unroll
      for (int rb = 0; rb < 2; ++rb)
#pragma unroll
        for (int cb = 0; cb < 4; ++cb)
          acc[rb][cb] = __builtin_amdgcn_mfma_f32_16x16x32_bf16(a[rb][ks], b[cb][ks], acc[rb][cb], 0, 0, 0);
  }

  // epilogue: z = 10*sims; per-row partial max/sumexp over this block's 128 cols
  const int gcol0 = colblk * 128 + wc * 64;
#pragma unroll
  for (int rb = 0; rb < 2; ++rb) {
#pragma unroll
    for (int r = 0; r < 4; ++r) {
      const int lrow = wr * 32 + rb * 16 + quad * 4 + r;
      float zv[4];
      float m = -1e30f;
#pragma unroll
      for (int cb = 0; cb < 4; ++cb) {
        float z = acc[rb][cb][r] * TEMP_INV;
        int gc = gcol0 + cb * 16 + l15;
        if (gc == lab[lrow]) ztrue[rowblk * 64 + lrow] = z;
        if (gc >= NCLS) z = -1e30f;
        zv[cb] = z;
        m = fmaxf(m, z);
      }
#pragma unroll
      for (int msk = 1; msk < 16; msk <<= 1) m = fmaxf(m, __shfl_xor(m, msk));
      float s = 0.f;
#pragma unroll
      for (int cb = 0; cb < 4; ++cb) s += __expf(zv[cb] - m);
#pragma unroll
      for (int msk = 1; msk < 16; msk <<= 1) s += __shfl_xor(s, msk);
      if (l15 == 0) { sm[lrow][wc] = m; ss[lrow][wc] = s; }
    }
  }
  __syncthreads();
  if (t < 64) {
    float m0 = sm[t][0], m1 = sm[t][1];
    float mn = fmaxf(m0, m1);
    float S = ss[t][0] * __expf(m0 - mn) + ss[t][1] * __expf(m1 - mn);
    int grow = rowblk * 64 + t;
    pm[colblk * B_ROWS + grow] = mn;
    psv[colblk * B_ROWS + grow] = S;
  }
}

// ---------------- combine: merge partials -> p, SDC partials, class buckets
__global__ __launch_bounds__(256) void combine_kernel(
    const float* __restrict__ pm, const float* __restrict__ psv,
    const float* __restrict__ ztrue, const int* __restrict__ labels,
    int* __restrict__ bcnt, int* __restrict__ bidx, float* __restrict__ bp,
    float* __restrict__ sdc_partial) {
  __shared__ float wred[4];
  const int b = blockIdx.x * 256 + threadIdx.x;
  float mj[8];
  float M = -1e30f;
#pragma unroll
  for (int j = 0; j < 8; ++j) { mj[j] = pm[j * B_ROWS + b]; M = fmaxf(M, mj[j]); }
  float S = 0.f;
#pragma unroll
  for (int j = 0; j < 8; ++j) S += psv[j * B_ROWS + b] * __expf(mj[j] - M);
  float p = __expf(ztrue[b] - M) / S;
  int lb = labels[b];
  int slot = atomicAdd(&bcnt[lb], 1);
  if (slot < BCAP) { bidx[lb * BCAP + slot] = b; bp[lb * BCAP + slot] = p; }
  float v = -logf(p + 1e-8f);
#pragma unroll
  for (int msk = 1; msk < 64; msk <<= 1) v += __shfl_xor(v, msk);
  if ((threadIdx.x & 63) == 0) wred[threadIdx.x >> 6] = v;
  __syncthreads();
  if (threadIdx.x == 0)
    sdc_partial[blockIdx.x] = wred[0] + wred[1] + wred[2] + wred[3];
}

// ---------------- mstep: one block per class, direct bucket gather.
// Block 0 additionally finalizes the scalar loss.
__global__ __launch_bounds__(256) void mstep_kernel(
    const float* __restrict__ features,
    const float* __restrict__ centers,
    const int* __restrict__ bcnt, const int* __restrict__ bidx,
    const float* __restrict__ bp,
    const float* __restrict__ ce_partial, const float* __restrict__ sdc_partial,
    float* __restrict__ out_loss, float* __restrict__ out_centers) {
  const int c = blockIdx.x;
  const int t = threadIdx.x;
  if (c == 0) {
    __shared__ float red[256];
    float s = 0.f;
    for (int i = t; i < CE_BLOCKS; i += 256) s += ce_partial[i];
    float s2 = 0.f;
    for (int i = t; i < 64; i += 256) s2 += sdc_partial[i];
    red[t] = s + 0.1f * s2;
    __syncthreads();
    for (int off = 128; off > 0; off >>= 1) {
      if (t < off) red[t] += red[t + off];
      __syncthreads();
    }
    if (t == 0) out_loss[0] = red[0] * (1.0f / 16384.0f);
  }
  int n = bcnt[c];
  if (n > BCAP) n = BCAP;
  float a0 = 0.f, a1 = 0.f, a2 = 0.f, ws = 0.f;
  int j = 0;
  for (; j + 2 <= n; j += 2) {
    int b0 = bidx[c * BCAP + j], b1 = bidx[c * BCAP + j + 1];
    float p0 = bp[c * BCAP + j], p1 = bp[c * BCAP + j + 1];
    const float* f0 = features + (size_t)b0 * FDIM;
    const float* f1 = features + (size_t)b1 * FDIM;
    float x00 = f0[t], x01 = f0[t + 256], x02 = f0[t + 512];
    float x10 = f1[t], x11 = f1[t + 256], x12 = f1[t + 512];
    a0 += p0 * x00 + p1 * x10;
    a1 += p0 * x01 + p1 * x11;
    a2 += p0 * x02 + p1 * x12;
    ws += p0 + p1;
  }
  if (j < n) {
    int b0 = bidx[c * BCAP + j];
    float p0 = bp[c * BCAP + j];
    const float* f0 = features + (size_t)b0 * FDIM;
    a0 += p0 * f0[t]; a1 += p0 * f0[t + 256]; a2 += p0 * f0[t + 512];
    ws += p0;
  }
  const float* crow = centers + (size_t)c * FDIM;
  float c0 = crow[t], c1 = crow[t + 256], c2 = crow[t + 512];
  size_t o = (size_t)c * FDIM + t;
  if (ws > 0.f) {
    float inv = 0.1f / (ws + 1e-8f);
    out_centers[o]       = 0.9f * c0 + a0 * inv;
    out_centers[o + 256] = 0.9f * c1 + a1 * inv;
    out_centers[o + 512] = 0.9f * c2 + a2 * inv;
  } else {
    out_centers[o]       = c0;
    out_centers[o + 256] = c1;
    out_centers[o + 512] = c2;
  }
}

extern "C" void kernel_launch(void* const* d_in, const int* in_sizes, int n_in,
                              void* d_out, int out_size, void* d_ws, size_t ws_size,
                              hipStream_t stream) {
  const float* outputs  = (const float*)d_in[0];
  const int*   labels   = (const int*)d_in[1];
  const float* features = (const float*)d_in[2];
  const float* centers  = (const float*)d_in[3];
  float* out = (float*)d_out;

  char* ws = (char*)d_ws;
  float* ztrue       = (float*)(ws);                          // 64 KB
  float* ce_partial  = (float*)(ws + (64 << 10));             // 16 KB
  float* sdc_partial = (float*)(ws + (80 << 10));             // 256 B
  int*   bcnt        = (int*)(ws + (84 << 10));               // 4 KB
  float* pm          = (float*)(ws + (88 << 10));             // 512 KB
  float* psv         = (float*)(ws + (600 << 10));            // 512 KB
  unsigned short* cbf = (unsigned short*)(ws + (1112 << 10)); // 1.5 MB
  unsigned short* fbf = (unsigned short*)(ws + (2648 << 10)); // 24 MB
  // buckets overlay fbf (dead after gemm; written in combine, read in mstep)
  int*   bidx        = (int*)(ws + (2648 << 10));             // 512 KB
  float* bp          = (float*)(ws + (3160 << 10));           // 512 KB

  cvt_kernel<<<CVT_BLOCKS, 256, 0, stream>>>(features, centers, fbf, cbf);
  gemm_stats_kernel<<<GEMM_BLOCKS + CE_BLOCKS, 256, 0, stream>>>(
      fbf, cbf, labels, outputs, ce_partial, pm, psv, ztrue, bcnt);
  combine_kernel<<<B_ROWS / 256, 256, 0, stream>>>(pm, psv, ztrue, labels,
                                                   bcnt, bidx, bp, sdc_partial);
  mstep_kernel<<<NCLS, 256, 0, stream>>>(features, centers, bcnt, bidx, bp,
                                         ce_partial, sdc_partial, out, out + 1);
}